// Round 2
// baseline (119.196 us; speedup 1.0000x reference)
//
#include <hip/hip_runtime.h>
#include <hip/hip_bf16.h>

#define NB   16384
#define ND   2048
#define NG   8
#define NR   6
#define NKC  48
#define NOUT 54
#define BM   32
#define KC   256
#define NCH  (ND / KC)          // 8 chunks
#define LROW 264                // shorts; 528B row stride: 16B-aligned, dword-stride 132 ≡ 4 (mod 32)
#define MAXT (NB / BM + NG)     // 520 tiles max

typedef __attribute__((ext_vector_type(8))) short short8_t;
typedef __attribute__((ext_vector_type(4))) float f32x4;

__device__ __forceinline__ unsigned short f2bf(float x) {
    union { float f; unsigned u; } v; v.f = x;
    unsigned r = v.u + 0x7FFFu + ((v.u >> 16) & 1u);   // RNE
    return (unsigned short)(r >> 16);
}

__device__ __forceinline__ short8_t cvt8(float4 a, float4 b) {
    short8_t s;
    s[0] = (short)f2bf(a.x); s[1] = (short)f2bf(a.y);
    s[2] = (short)f2bf(a.z); s[3] = (short)f2bf(a.w);
    s[4] = (short)f2bf(b.x); s[5] = (short)f2bf(b.y);
    s[6] = (short)f2bf(b.z); s[7] = (short)f2bf(b.w);
    return s;
}

// ---- 2-pass path: histogram ----
__global__ void hist_kernel(const int* __restrict__ roi, int* __restrict__ counts) {
    int i = blockIdx.x * 256 + threadIdx.x;
    int g = roi[i];
    int lane = threadIdx.x & 63;
    #pragma unroll
    for (int gg = 0; gg < NG; ++gg) {
        unsigned long long m = __ballot(g == gg);
        if (m && lane == (int)(__ffsll((unsigned long long)m) - 1))
            atomicAdd(&counts[gg], (int)__popcll(m));
    }
}

// ---- 2-pass path: scatter into packed regions ----
__global__ void scatter_kernel(const int* __restrict__ roi, const int* __restrict__ counts,
                               int* __restrict__ ranks, int* __restrict__ perm) {
    int off[NG];
    int acc = 0;
    #pragma unroll
    for (int gg = 0; gg < NG; ++gg) { off[gg] = acc; acc += counts[gg]; }
    int i = blockIdx.x * 256 + threadIdx.x;
    int g = roi[i];
    int lane = threadIdx.x & 63;
    #pragma unroll
    for (int gg = 0; gg < NG; ++gg) {
        unsigned long long m = __ballot(g == gg);
        if (!m) continue;
        int leader = (int)(__ffsll((unsigned long long)m) - 1);
        int base = 0;
        if (lane == leader) base = atomicAdd(&ranks[gg], (int)__popcll(m));
        base = __shfl(base, leader);
        if (g == gg) {
            int rank = (int)__popcll(m & ((1ull << lane) - 1ull));
            perm[off[gg] + base + rank] = i;
        }
    }
}

// ---- 1-pass path: scatter into fixed per-group regions of stride NB ----
__global__ void scatter1_kernel(const int* __restrict__ roi, int* __restrict__ cnt,
                                int* __restrict__ perm) {
    int i = blockIdx.x * 256 + threadIdx.x;
    int g = roi[i];
    int lane = threadIdx.x & 63;
    #pragma unroll
    for (int gg = 0; gg < NG; ++gg) {
        unsigned long long m = __ballot(g == gg);
        if (!m) continue;
        int leader = (int)(__ffsll((unsigned long long)m) - 1);
        int base = 0;
        if (lane == leader) base = atomicAdd(&cnt[gg], (int)__popcll(m));
        base = __shfl(base, leader);
        if (g == gg) {
            int rank = (int)__popcll(m & ((1ull << lane) - 1ull));
            perm[gg * NB + base + rank] = i;
        }
    }
}

// ---- grouped skinny GEMM: A direct from global, B double-buffered in LDS ----
__launch_bounds__(256, 2)
__global__ void gemm_kernel(const float* __restrict__ feats,
                            const float* __restrict__ Wreg, const float* __restrict__ breg,
                            const float* __restrict__ Wcls, const float* __restrict__ bcls,
                            const int* __restrict__ counts, const int* __restrict__ perm,
                            float* __restrict__ out, int stride) {
    __shared__ __align__(16) short Bs[2][64][LROW];
    __shared__ int sRow[BM];

    int ts[NG + 1]; ts[0] = 0;
    int off[NG]; int acc = 0;
    #pragma unroll
    for (int gg = 0; gg < NG; ++gg) {
        int c = counts[gg];
        off[gg] = stride ? gg * stride : acc;
        acc += c;
        ts[gg + 1] = ts[gg] + (c + BM - 1) / BM;
    }
    int b = blockIdx.x;
    if (b >= ts[NG]) return;
    int g = 0;
    #pragma unroll
    for (int gg = 0; gg < NG; ++gg) if (b >= ts[gg + 1]) g = gg + 1;
    int gcnt  = counts[g];
    int goff  = off[g];
    int rbase = (b - ts[g]) * BM;
    int nvalid = gcnt - rbase; if (nvalid > BM) nvalid = BM;

    int tid = threadIdx.x;
    if (tid < BM) {
        int r = rbase + tid;
        if (r >= gcnt) r = gcnt - 1;   // clamp; stores masked by nvalid
        sRow[tid] = perm[goff + r];
    }
    __syncthreads();

    // B staging role: thread t stages row rB, column-quarter c4 (granules c4+4i)
    int rB = (tid & 15) | ((tid >> 6) << 4);
    int c4 = (tid >> 4) & 3;
    const float* wsrc = nullptr;
    if (rB < NR)        wsrc = Wreg + ((size_t)g * NR + rB) * ND + c4 * 8;
    else if (rB < NOUT) wsrc = Wcls + ((size_t)g * NKC + (rB - NR)) * ND + c4 * 8;
    short* bw = &Bs[0][rB][c4 * 8];                 // buffer 1 at +64*LROW shorts

    // wave/frag roles: 4 waves = 2 m-tiles x 2 n-halves
    int w = tid >> 6, l = tid & 63, lr = l & 15, lq = l >> 4;
    int mt = w & 1, nh = w >> 1;
    const float* aptr = feats + (size_t)sRow[mt * 16 + lr] * ND + lq * 8;
    const short* br0 = &Bs[0][nh * 32 + lr][lq * 8];

    f32x4 acc0 = {0, 0, 0, 0}, acc1 = {0, 0, 0, 0};
    float4 rb[16];
    #pragma unroll
    for (int i = 0; i < 16; ++i) rb[i] = make_float4(0.f, 0.f, 0.f, 0.f);

    // prologue: stage B chunk 0
    if (wsrc) {
        #pragma unroll
        for (int i = 0; i < 8; ++i) {
            rb[2 * i]     = *(const float4*)(wsrc + 32 * i);
            rb[2 * i + 1] = *(const float4*)(wsrc + 32 * i + 4);
        }
    }
    #pragma unroll
    for (int i = 0; i < 8; ++i)
        *(short8_t*)(bw + 32 * i) = cvt8(rb[2 * i], rb[2 * i + 1]);
    __syncthreads();

    int bufoff = 0;
    for (int c = 0; c < NCH; ++c) {
        // issue next chunk's B loads early (consumed after the MFMA phase)
        if (c + 1 < NCH && wsrc) {
            const float* s = wsrc + (c + 1) * KC;
            #pragma unroll
            for (int i = 0; i < 8; ++i) {
                rb[2 * i]     = *(const float4*)(s + 32 * i);
                rb[2 * i + 1] = *(const float4*)(s + 32 * i + 4);
            }
        }
        // MFMA phase: A straight from global (fp32 -> bf16 in reg), B from LDS
        const float* ap = aptr + c * KC;
        const short* bp = br0 + bufoff;
        #pragma unroll
        for (int ks = 0; ks < 8; ++ks) {
            float4 a0 = *(const float4*)(ap + ks * 32);
            float4 a1 = *(const float4*)(ap + ks * 32 + 4);
            short8_t af = cvt8(a0, a1);
            short8_t b0 = *(const short8_t*)(bp + ks * 32);
            short8_t b1 = *(const short8_t*)(bp + 16 * LROW + ks * 32);
            acc0 = __builtin_amdgcn_mfma_f32_16x16x32_bf16(af, b0, acc0, 0, 0, 0);
            acc1 = __builtin_amdgcn_mfma_f32_16x16x32_bf16(af, b1, acc1, 0, 0, 0);
        }
        // write next chunk into the other buffer, then one barrier
        if (c + 1 < NCH) {
            short* bwd = bw + (bufoff ^ (64 * LROW));
            #pragma unroll
            for (int i = 0; i < 8; ++i)
                *(short8_t*)(bwd + 32 * i) = cvt8(rb[2 * i], rb[2 * i + 1]);
        }
        __syncthreads();
        bufoff ^= 64 * LROW;
    }

    // epilogue: bias + scatter to routed rows
    const int B6 = NB * NR;
    #pragma unroll
    for (int n = 0; n < 2; ++n) {
        f32x4 v = n ? acc1 : acc0;
        int col = nh * 32 + n * 16 + lr;
        if (col < NOUT) {
            #pragma unroll
            for (int j = 0; j < 4; ++j) {
                int row = mt * 16 + lq * 4 + j;
                if (row < nvalid) {
                    int smp = sRow[row];
                    if (col < NR) out[smp * NR + col] = v[j] + breg[g * NR + col];
                    else          out[B6 + smp * NKC + (col - NR)] = v[j] + bcls[g * NKC + (col - NR)];
                }
            }
        }
    }
}

// ---- fallback (ws too small): exact fp32, one wave per sample ----
__global__ void fallback_kernel(const float* __restrict__ feats, const int* __restrict__ roi,
                                const float* __restrict__ Wreg, const float* __restrict__ breg,
                                const float* __restrict__ Wcls, const float* __restrict__ bcls,
                                float* __restrict__ out) {
    int i = blockIdx.x;
    int lane = threadIdx.x;
    int g = roi[i];
    const float* frow = feats + (size_t)i * ND;
    float f[32];
    #pragma unroll
    for (int q = 0; q < 32; ++q) f[q] = frow[lane + 64 * q];
    for (int o = 0; o < NOUT; ++o) {
        const float* wrow = (o < NR) ? Wreg + ((size_t)g * NR + o) * ND
                                     : Wcls + ((size_t)g * NKC + (o - NR)) * ND;
        float p = 0.f;
        #pragma unroll
        for (int q = 0; q < 32; ++q) p += f[q] * wrow[lane + 64 * q];
        #pragma unroll
        for (int s = 32; s; s >>= 1) p += __shfl_xor(p, s);
        if (lane == 0) {
            if (o < NR) out[i * NR + o] = p + breg[g * NR + o];
            else        out[NB * NR + i * NKC + (o - NR)] = p + bcls[g * NKC + (o - NR)];
        }
    }
}

extern "C" void kernel_launch(void* const* d_in, const int* in_sizes, int n_in,
                              void* d_out, int out_size, void* d_ws, size_t ws_size,
                              hipStream_t stream) {
    const float* feats = (const float*)d_in[0];
    const int*   roi   = (const int*)d_in[1];
    const float* Wreg  = (const float*)d_in[2];
    const float* breg  = (const float*)d_in[3];
    const float* Wcls  = (const float*)d_in[4];
    const float* bcls  = (const float*)d_in[5];
    float* out = (float*)d_out;

    size_t need1 = (size_t)(64 + NG * NB) * sizeof(int);   // 1-pass: fixed-stride perm
    size_t need2 = (size_t)(64 + NB) * sizeof(int);        // 2-pass: packed perm

    if (ws_size >= need1) {
        int* cnt  = (int*)d_ws;
        int* perm = cnt + 64;
        hipMemsetAsync(cnt, 0, 8 * sizeof(int), stream);
        scatter1_kernel<<<NB / 256, 256, 0, stream>>>(roi, cnt, perm);
        gemm_kernel<<<MAXT, 256, 0, stream>>>(feats, Wreg, breg, Wcls, bcls, cnt, perm, out, NB);
    } else if (ws_size >= need2) {
        int* counts = (int*)d_ws;
        int* ranks  = counts + 8;
        int* perm   = counts + 64;
        hipMemsetAsync(counts, 0, 16 * sizeof(int), stream);
        hist_kernel<<<NB / 256, 256, 0, stream>>>(roi, counts);
        scatter_kernel<<<NB / 256, 256, 0, stream>>>(roi, counts, ranks, perm);
        gemm_kernel<<<MAXT, 256, 0, stream>>>(feats, Wreg, breg, Wcls, bcls, counts, perm, out, 0);
    } else {
        fallback_kernel<<<NB, 64, 0, stream>>>(feats, roi, Wreg, breg, Wcls, bcls, out);
    }
}